// Round 21
// baseline (344.763 us; speedup 1.0000x reference)
//
#include <hip/hip_runtime.h>

#define NNODES 100000
#define NEDGES 1600000
#define FDIM 128
#define NGRAPHS 128
#define NLAYERS 4
#define NCLASS 10
#define GLDC 72     // gemm epilogue LDS row stride: 72 elems (bf16) / 72 bytes (fp8)
#define NBUCK 391   // buckets of 256 nodes: dst>>8, 391*256 = 100096 >= 100000
#define EBCAP 5120  // per-bucket edge capacity: mean 4090, sigma 64 -> +16 sigma
#define EPB 2048    // edges per block in scatter kernel (782 blocks = 3.05/CU)
#define NBLK_E ((NEDGES + EPB - 1) / EPB)

typedef __attribute__((ext_vector_type(8))) short bf16x8;
typedef __attribute__((ext_vector_type(4))) float f32x4;
typedef __attribute__((ext_vector_type(2))) float f32x2;
typedef unsigned char u8;
typedef unsigned short u16;
typedef unsigned int u32;
typedef unsigned long long u64;

__device__ __forceinline__ u16 f2bf(float f) {
    u32 u = __float_as_uint(f);
    u += 0x7fffu + ((u >> 16) & 1u);   // round-to-nearest-even
    return (u16)(u >> 16);
}
__device__ __forceinline__ u32 pack_bf(float a, float b) {
    return (u32)f2bf(a) | ((u32)f2bf(b) << 16);
}

// async global->LDS, 16 B per lane; LDS dest = uniform base + lane*16
__device__ __forceinline__ void gload_lds16(const u16* g, u16* l) {
    __builtin_amdgcn_global_load_lds(
        (const __attribute__((address_space(1))) u32*)g,
        (__attribute__((address_space(3))) u32*)l, 16, 0, 0);
}

// ---------------- dtype conversion ----------------

__global__ __launch_bounds__(256) void conv_x(const float* __restrict__ x,
                                              u16* __restrict__ xb,
                                              u8* __restrict__ x8) {
    int i = (blockIdx.x * 256 + threadIdx.x) * 4;
    if (i < NNODES * FDIM) {
        float4 v = *(const float4*)(x + i);
        u32 p0 = pack_bf(v.x, v.y), p1 = pack_bf(v.z, v.w);
        *(u32*)(xb + i) = p0;
        *(u32*)(xb + i + 2) = p1;
        u32 a = (u32)__builtin_amdgcn_cvt_pk_fp8_f32(v.x, v.y, 0, 0);
        u32 b = (u32)__builtin_amdgcn_cvt_pk_fp8_f32(v.z, v.w, 0, 0);
        *(u32*)(x8 + i) = (a & 0xffffu) | (b << 16);
    }
}

// Wcat[l][n][k]: k<128 -> Wrel[k][n], k>=128 -> Wroot[k-128][n]  (transposed, concat)
__global__ __launch_bounds__(256) void conv_w(const float* __restrict__ W1_rel,
                                              const float* __restrict__ W1_root,
                                              const float* __restrict__ Wc_rel,
                                              const float* __restrict__ Wc_root,
                                              u16* __restrict__ Wcat) {
    int idx = blockIdx.x * 256 + threadIdx.x;
    if (idx >= NLAYERS * 256 * FDIM) return;
    int n = idx & 127;
    int k = (idx >> 7) & 255;
    int l = idx >> 15;
    const float* Wr = (l == 0) ? W1_rel  : Wc_rel  + (size_t)(l - 1) * FDIM * FDIM;
    const float* Wt = (l == 0) ? W1_root : Wc_root + (size_t)(l - 1) * FDIM * FDIM;
    float v = (k < 128) ? Wr[(size_t)k * FDIM + n] : Wt[(size_t)(k - 128) * FDIM + n];
    Wcat[(size_t)l * 32768 + (size_t)n * 256 + k] = f2bf(v);
}

// ---------------- setup: graph ptr (binary search) + bucket cursor init, one launch -----

__global__ __launch_bounds__(512) void setup_kernel(const int* __restrict__ batch,
                                                    int* __restrict__ gptr,
                                                    int* __restrict__ bcur) {
    int t = threadIdx.x;
    if (t < NBUCK) bcur[t] = t * EBCAP;
    if (t <= NGRAPHS) {
        int lo = 0, hi = NNODES;
        while (lo < hi) {
            int mid = (lo + hi) >> 1;
            if (batch[mid] < t) lo = mid + 1; else hi = mid;
        }
        gptr[t] = lo;
    }
}

// scatter packed (dst,src) records into fixed-capacity per-bucket streams.
// EPB=2048 (3.05 blocks/CU) + register-cached edges: dst/src read exactly once.
__global__ __launch_bounds__(256) void bucket_scatter(const int* __restrict__ src,
                                                      const int* __restrict__ dst,
                                                      int* __restrict__ bcur,
                                                      u64* __restrict__ ebuf) {
    __shared__ int cnt[NBUCK];
    for (int i = threadIdx.x; i < NBUCK; i += 256) cnt[i] = 0;
    __syncthreads();
    const int e0 = blockIdx.x * EPB + threadIdx.x;
    int d[8], s[8];
#pragma unroll
    for (int i = 0; i < 8; ++i) {
        int e = e0 + i * 256;
        bool ok = e < NEDGES;
        d[i] = ok ? dst[e] : -1;
        s[i] = ok ? src[e] : 0;
        if (ok) atomicAdd(&cnt[d[i] >> 8], 1);
    }
    __syncthreads();
    for (int i = threadIdx.x; i < NBUCK; i += 256) {
        int c = cnt[i];
        if (c) cnt[i] = atomicAdd(&bcur[i], c);   // cnt[i] becomes the block's base cursor
    }
    __syncthreads();
#pragma unroll
    for (int i = 0; i < 8; ++i) {
        if (d[i] >= 0) {
            int pos = atomicAdd(&cnt[d[i] >> 8], 1);
            ebuf[pos] = ((u64)(u32)d[i] << 32) | (u32)s[i];
        }
    }
}

// one block per bucket: stage edges in LDS (one global read), count + scan -> rowstart/
// rowend, scatter src into bucket's csr slice.
__global__ __launch_bounds__(256) void bucket_csr(const u64* __restrict__ ebuf,
                                                  const int* __restrict__ bcur,
                                                  int* __restrict__ rowstart,
                                                  int* __restrict__ rowend,
                                                  int* __restrict__ csr) {
    __shared__ u64 eb[EBCAP];          // 40 KB
    __shared__ int cur[256];
    __shared__ int sd[256];
    int b = blockIdx.x, t = threadIdx.x;
    int ebase = b * EBCAP, eend = bcur[b];
    int ne = eend - ebase;
    int n0 = b << 8;
    cur[t] = 0;
    for (int e = t; e < ne; e += 256) eb[e] = ebuf[ebase + e];
    __syncthreads();
    for (int e = t; e < ne; e += 256) {
        int d = (int)(eb[e] >> 32);
        atomicAdd(&cur[d & 255], 1);
    }
    __syncthreads();
    int v = cur[t];
    sd[t] = v;
    __syncthreads();
    for (int s = 1; s < 256; s <<= 1) {
        int add = (t >= s) ? sd[t - s] : 0;
        __syncthreads();
        sd[t] += add;
        __syncthreads();
    }
    int excl = sd[t] - v;
    cur[t] = ebase + excl;
    if (n0 + t < NNODES) {
        rowstart[n0 + t] = ebase + excl;
        rowend[n0 + t]   = ebase + excl + v;
    }
    __syncthreads();
    for (int e = t; e < ne; e += 256) {
        u64 r = eb[e];
        int d = (int)(r >> 32);
        int pos = atomicAdd(&cur[d & 255], 1);
        csr[pos] = (int)(r & 0xffffffffu);
    }
}

// ---------------- aggregation: one wave per node, fp8 gather (128 B/row) ----------------
// Tail batch: loads stay 16-deep (MLP preserved); arithmetic guarded by a WAVE-UNIFORM
// branch per slot (cnt is wave-uniform) -> dead cvt/fma skipped, bit-identical result.

__global__ __launch_bounds__(256) void agg_bf(const u8* __restrict__ h8,
                                              const int* __restrict__ rowstart,
                                              const int* __restrict__ rowend,
                                              const int* __restrict__ csr,
                                              u16* __restrict__ agg) {
    int wave = threadIdx.x >> 6;
    int lane = threadIdx.x & 63;
    int node = (blockIdx.x << 2) + wave;
    if (node >= NNODES) return;
    int e0 = rowstart[node], e1 = rowend[node];
    int cnt = e1 - e0;
    float ax = 0.f, ay = 0.f;
    if (cnt <= 64) {
        int myidx = (lane < cnt) ? csr[e0 + lane] : 0;
        int nb = (cnt + 15) >> 4;
        for (int b = 0; b < nb; ++b) {
            int base = b * 16;
            u32 vv[16];
#pragma unroll
            for (int i = 0; i < 16; ++i) {
                int s = __builtin_amdgcn_readlane(myidx, base + i);
                vv[i] = *(const u16*)(h8 + (size_t)s * FDIM + lane * 2);
            }
            if (base + 16 <= cnt) {
#pragma unroll
                for (int i = 0; i < 16; ++i) {
                    f32x2 f = __builtin_amdgcn_cvt_pk_f32_fp8((int)vv[i], 0);
                    ax += f.x; ay += f.y;
                }
            } else {
#pragma unroll
                for (int i = 0; i < 16; ++i) {
                    if (base + i < cnt) {       // wave-uniform: skips dead slots entirely
                        f32x2 f = __builtin_amdgcn_cvt_pk_f32_fp8((int)vv[i], 0);
                        ax += f.x; ay += f.y;
                    }
                }
            }
        }
    } else {
        int e = e0;
        for (; e + 8 <= e1; e += 8) {
            u32 v0 = *(const u16*)(h8 + (size_t)csr[e]     * FDIM + lane * 2);
            u32 v1 = *(const u16*)(h8 + (size_t)csr[e + 1] * FDIM + lane * 2);
            u32 v2 = *(const u16*)(h8 + (size_t)csr[e + 2] * FDIM + lane * 2);
            u32 v3 = *(const u16*)(h8 + (size_t)csr[e + 3] * FDIM + lane * 2);
            u32 v4 = *(const u16*)(h8 + (size_t)csr[e + 4] * FDIM + lane * 2);
            u32 v5 = *(const u16*)(h8 + (size_t)csr[e + 5] * FDIM + lane * 2);
            u32 v6 = *(const u16*)(h8 + (size_t)csr[e + 6] * FDIM + lane * 2);
            u32 v7 = *(const u16*)(h8 + (size_t)csr[e + 7] * FDIM + lane * 2);
            f32x2 f0 = __builtin_amdgcn_cvt_pk_f32_fp8((int)v0, 0);
            f32x2 f1 = __builtin_amdgcn_cvt_pk_f32_fp8((int)v1, 0);
            f32x2 f2 = __builtin_amdgcn_cvt_pk_f32_fp8((int)v2, 0);
            f32x2 f3 = __builtin_amdgcn_cvt_pk_f32_fp8((int)v3, 0);
            f32x2 f4 = __builtin_amdgcn_cvt_pk_f32_fp8((int)v4, 0);
            f32x2 f5 = __builtin_amdgcn_cvt_pk_f32_fp8((int)v5, 0);
            f32x2 f6 = __builtin_amdgcn_cvt_pk_f32_fp8((int)v6, 0);
            f32x2 f7 = __builtin_amdgcn_cvt_pk_f32_fp8((int)v7, 0);
            ax += f0.x + f1.x + f2.x + f3.x + f4.x + f5.x + f6.x + f7.x;
            ay += f0.y + f1.y + f2.y + f3.y + f4.y + f5.y + f6.y + f7.y;
        }
        for (; e < e1; ++e) {
            u32 v0 = *(const u16*)(h8 + (size_t)csr[e] * FDIM + lane * 2);
            f32x2 f = __builtin_amdgcn_cvt_pk_f32_fp8((int)v0, 0);
            ax += f.x; ay += f.y;
        }
    }
    ((u32*)(agg + (size_t)node * FDIM))[lane] = pack_bf(ax, ay);
}

// ---------------- MFMA GEMM, M+N-SPLIT: 64 rows x 64 cols per block ---------------------
// relu([agg|h] @ Wcat^T + b) -> hout (bf16) AND hout8 (fp8); per-graph sums into z.
// Grid = 1563 row-tiles x 2 col-halves = 3126 blocks. 4 waves (2x2), wave = 32x32
// (acc[2][2]). K=256 in 4 steps of 64. LDS 16.4 KB; resident = 8 blocks/CU (32 waves =
// occupancy cap). XOR chunk-swizzle on SOURCE and READ. last!=0: skip hout stores.

__global__ __launch_bounds__(256) void gemm_mfma(const u16* __restrict__ aggb,
                                                 const u16* __restrict__ hinb,
                                                 const u16* __restrict__ Wl,   // [128 n][256 k]
                                                 const float* __restrict__ bias,
                                                 const int* __restrict__ batch,
                                                 float* __restrict__ z, int layer, int last,
                                                 u16* __restrict__ houtb,
                                                 u8* __restrict__ hout8) {
    __shared__ u16 S[8192];             // 16384 B: As(8K)|Bs(8K); C aliases: bf16 9216 B
    __shared__ int batchs[64];          // (stride 72) + fp8 4608 B @ byte 9216 (stride 72)
    u16* As = S;                        // [64][64] bf16, swizzled 16B chunks
    u16* Bs = S + 4096;                 // [64][64] bf16 (this block's 64 W-columns)
    u8* Cs8 = (u8*)S + 9216;
    const int t = threadIdx.x;
    const int lane = t & 63;
    const int w = t >> 6;
    const int wr = w >> 1, wc = w & 1;
    const int row0 = (blockIdx.x >> 1) * 64;
    const int col0 = (blockIdx.x & 1) * 64;
    const int lr = lane & 15;

    const int srow = lane >> 3;         // staging: row 0..7 within 8-row group
    const int sq = lane & 7;            // staging: chunk slot 0..7

    f32x4 acc[2][2];
#pragma unroll
    for (int m = 0; m < 2; ++m)
#pragma unroll
        for (int n = 0; n < 2; ++n) acc[m][n] = (f32x4){0.f, 0.f, 0.f, 0.f};

    if (t < 64) batchs[t] = (row0 + t < NNODES) ? batch[row0 + t] : NGRAPHS;

    for (int kb = 0; kb < 4; ++kb) {
        const u16* xsrc = (kb < 2) ? aggb : hinb;
        const int koff = (kb & 1) * 64;
        // A: 8 blk8 sub-tiles (2 per wave), rows row0..row0+63
#pragma unroll
        for (int i = 0; i < 2; ++i) {
            int blk8 = w * 2 + i;
            int r = blk8 * 8 + srow;            // 0..63 local
            int sc = sq ^ (r & 7);
            int arow = row0 + r; if (arow > NNODES - 1) arow = NNODES - 1;
            gload_lds16(xsrc + (size_t)arow * FDIM + koff + sc * 8, As + blk8 * 512);
        }
        // B: 8 blk8 sub-tiles (2 per wave), W rows col0..col0+63
#pragma unroll
        for (int i = 0; i < 2; ++i) {
            int blk8 = w * 2 + i;
            int r = blk8 * 8 + srow;            // 0..63 local
            int sc = sq ^ (r & 7);
            gload_lds16(Wl + (size_t)(col0 + r) * 256 + kb * 64 + sc * 8, Bs + blk8 * 512);
        }
        __syncthreads();                        // drains vmcnt -> LDS tiles ready
#pragma unroll
        for (int ks = 0; ks < 2; ++ks) {
            bf16x8 a[2], b[2];
            int qr = ks * 4 + (lane >> 4);      // logical chunk 0..7
#pragma unroll
            for (int m = 0; m < 2; ++m) {
                int r = wr * 32 + m * 16 + lr;  // 0..63 local row
                int ch = qr ^ (r & 7);
                a[m] = *(const bf16x8*)&As[r * 64 + ch * 8];
            }
#pragma unroll
            for (int n = 0; n < 2; ++n) {
                int r = wc * 32 + n * 16 + lr;  // 0..63 local W-row (= output col)
                int ch = qr ^ (r & 7);
                b[n] = *(const bf16x8*)&Bs[r * 64 + ch * 8];
            }
#pragma unroll
            for (int m = 0; m < 2; ++m)
#pragma unroll
                for (int n = 0; n < 2; ++n)
                    acc[m][n] = __builtin_amdgcn_mfma_f32_16x16x32_bf16(a[m], b[n], acc[m][n], 0, 0, 0);
        }
        __syncthreads();
    }
    // epilogue: bias + relu; repack bf16 + fp8 via aliased LDS (single pass)
#pragma unroll
    for (int m = 0; m < 2; ++m) {
#pragma unroll
        for (int n = 0; n < 2; ++n) {
            int cl = wc * 32 + n * 16 + lr;     // local col 0..63
            float bb = bias[col0 + cl];
#pragma unroll
            for (int reg = 0; reg < 4; ++reg) {
                int row = wr * 32 + m * 16 + (lane >> 4) * 4 + reg;  // 0..63 local
                float v = fmaxf(acc[m][n][reg] + bb, 0.f);
                S[row * GLDC + cl] = f2bf(v);
                Cs8[row * GLDC + cl] = (u8)__builtin_amdgcn_cvt_pk_fp8_f32(v, v, 0, 0);
            }
        }
    }
    __syncthreads();
    // coalesced global stores (bf16 + fp8) — dead on the last layer
    if (!last) {
        int r = t >> 2, q = t & 3;              // 64 rows x 4 threads; 16 cols (32 B) each
        if (row0 + r < NNODES) {
#pragma unroll
            for (int j = 0; j < 2; ++j) {       // 2 x 16 B = 32 B bf16
                bf16x8 v = *(const bf16x8*)&S[r * GLDC + q * 16 + j * 8];
                *(bf16x8*)(houtb + (size_t)(row0 + r) * FDIM + col0 + q * 16 + j * 8) = v;
            }
#pragma unroll
            for (int j = 0; j < 2; ++j) {       // 2 x 8 B = 16 B fp8
                u64 v8 = *(const u64*)&Cs8[r * GLDC + q * 16 + j * 8];
                *(u64*)(hout8 + (size_t)(row0 + r) * FDIM + col0 + q * 16 + j * 8) = v8;
            }
        }
    }
    // fused pool: 4 segments of 16 rows, one thread per (col, segment)
    {
        int col = t & 63, seg = t >> 6;
        int r0 = seg * 16, r1 = r0 + 16;
        float* zl = z + (size_t)layer * FDIM + col0 + col;
        int g = batchs[r0];
        float s = 0.f;
        for (int r = r0; r < r1; ++r) {
            int gn = batchs[r];
            if (gn != g) {
                atomicAdd(zl + (size_t)g * (NLAYERS * FDIM), s);
                s = 0.f; g = gn;
            }
            s += __uint_as_float((u32)S[r * GLDC + col] << 16);   // bf16 -> f32
        }
        atomicAdd(zl + (size_t)g * (NLAYERS * FDIM), s);
    }
}

// ---------------- final MLP (mean normalization folded into z load) ----------------

__global__ __launch_bounds__(128) void mlp1(const float* __restrict__ z,
                                            const int* __restrict__ gptr,
                                            const float* __restrict__ Wl1,
                                            const float* __restrict__ bl1,
                                            float* __restrict__ z2) {
    int g = blockIdx.x, j = threadIdx.x;
    __shared__ float zs[NLAYERS * FDIM];
    int cnt = gptr[g + 1] - gptr[g]; if (cnt < 1) cnt = 1;
    float invc = 1.0f / (float)cnt;
    for (int k = j; k < NLAYERS * FDIM; k += 128)
        zs[k] = z[(size_t)g * (NLAYERS * FDIM) + k] * invc;
    __syncthreads();
    float s = bl1[j];
    for (int k = 0; k < NLAYERS * FDIM; ++k) s = fmaf(zs[k], Wl1[(size_t)k * FDIM + j], s);
    z2[(size_t)g * FDIM + j] = fmaxf(s, 0.f);
}

__global__ __launch_bounds__(128) void mlp2(const float* __restrict__ z2,
                                            const float* __restrict__ Wl2,
                                            const float* __restrict__ bl2,
                                            float* __restrict__ out) {
    int g = blockIdx.x, c = threadIdx.x;
    __shared__ float zs[FDIM];
    if (threadIdx.x < FDIM) zs[threadIdx.x] = z2[(size_t)g * FDIM + threadIdx.x];
    __syncthreads();
    if (c < NCLASS) {
        float s = bl2[c];
        for (int k = 0; k < FDIM; ++k) s = fmaf(zs[k], Wl2[(size_t)k * NCLASS + c], s);
        out[(size_t)g * NCLASS + c] = s;
    }
}

// ---------------- launch ----------------

extern "C" void kernel_launch(void* const* d_in, const int* in_sizes, int n_in,
                              void* d_out, int out_size, void* d_ws, size_t ws_size,
                              hipStream_t stream) {
    const float* x       = (const float*)d_in[0];
    const int*   ei      = (const int*)d_in[1];
    const int*   batch   = (const int*)d_in[2];
    const float* W1_rel  = (const float*)d_in[3];
    const float* b1_rel  = (const float*)d_in[4];
    const float* W1_root = (const float*)d_in[5];
    const float* Wc_rel  = (const float*)d_in[6];
    const float* bc_rel  = (const float*)d_in[7];
    const float* Wc_root = (const float*)d_in[8];
    const float* Wl1     = (const float*)d_in[9];
    const float* bl1     = (const float*)d_in[10];
    const float* Wl2     = (const float*)d_in[11];
    const float* bl2     = (const float*)d_in[12];
    float* out = (float*)d_out;

    const int* srcv = ei;            // edge_index[0]
    const int* dstv = ei + NEDGES;   // edge_index[1]

    char* ws = (char*)d_ws;
    size_t off = 0;
    auto alloc = [&](size_t bytes) -> void* {
        void* p = ws + off;
        off = (off + bytes + 255) & ~(size_t)255;
        return p;
    };
    u16* xb      = (u16*)alloc((size_t)NNODES * FDIM * 2);
    u16* hA      = (u16*)alloc((size_t)NNODES * FDIM * 2);
    u16* hB      = (u16*)alloc((size_t)NNODES * FDIM * 2);
    u16* aggb    = (u16*)alloc((size_t)NNODES * FDIM * 2);
    u8*  x8      = (u8*)alloc((size_t)NNODES * FDIM);
    u8*  h8A     = (u8*)alloc((size_t)NNODES * FDIM);
    u8*  h8B     = (u8*)alloc((size_t)NNODES * FDIM);
    u16* Wcat    = (u16*)alloc((size_t)NLAYERS * 256 * FDIM * 2);
    int* csr     = (int*)alloc((size_t)NBUCK * EBCAP * 4);
    int* rowstart= (int*)alloc((size_t)NNODES * 4);
    int* rowend  = (int*)alloc((size_t)NNODES * 4);
    int* bcur    = (int*)alloc((size_t)(NBUCK + 1) * 4);
    int* gptr    = (int*)alloc(1024);
    float* z     = (float*)alloc((size_t)(NGRAPHS + 1) * NLAYERS * FDIM * 4);
    float* z2    = (float*)alloc((size_t)NGRAPHS * FDIM * 4);
    // ebuf (16.0 MB) aliases hA+hB region: build completes before layer 0 writes hA
    u64* ebuf    = (u64*)hA;
    (void)ws_size; (void)in_sizes; (void)n_in; (void)out_size;

    hipMemsetAsync(z, 0, (size_t)(NGRAPHS + 1) * NLAYERS * FDIM * 4, stream);
    conv_x<<<(NNODES * FDIM / 4 + 255) / 256, 256, 0, stream>>>(x, xb, x8);
    conv_w<<<(NLAYERS * 256 * FDIM + 255) / 256, 256, 0, stream>>>(W1_rel, W1_root, Wc_rel, Wc_root, Wcat);
    setup_kernel<<<1, 512, 0, stream>>>(batch, gptr, bcur);
    bucket_scatter<<<NBLK_E, 256, 0, stream>>>(srcv, dstv, bcur, ebuf);
    bucket_csr<<<NBUCK, 256, 0, stream>>>(ebuf, bcur, rowstart, rowend, csr);

    const u16* hin = xb;
    const u8*  hin8 = x8;
    const int gemm_nblk = ((NNODES + 63) / 64) * 2;
    for (int l = 0; l < NLAYERS; ++l) {
        u16* hout  = (l & 1) ? hB : hA;
        u8*  hout8 = (l & 1) ? h8B : h8A;
        const u16* Wl = Wcat + (size_t)l * 256 * FDIM;
        const float* bb = (l == 0) ? b1_rel : bc_rel + (size_t)(l - 1) * FDIM;
        agg_bf<<<(NNODES + 3) / 4, 256, 0, stream>>>(hin8, rowstart, rowend, csr, aggb);
        gemm_mfma<<<gemm_nblk, 256, 0, stream>>>(aggb, hin, Wl, bb, batch, z, l,
                                                 (l == NLAYERS - 1) ? 1 : 0, hout, hout8);
        hin = hout; hin8 = hout8;
    }
    mlp1<<<NGRAPHS, 128, 0, stream>>>(z, gptr, Wl1, bl1, z2);
    mlp2<<<NGRAPHS, 128, 0, stream>>>(z2, Wl2, bl2, out);
}

// Round 22
// 337.525 us; speedup vs baseline: 1.0214x; 1.0214x over previous
//
#include <hip/hip_runtime.h>

#define NNODES 100000
#define NEDGES 1600000
#define FDIM 128
#define NGRAPHS 128
#define NLAYERS 4
#define NCLASS 10
#define GLDC 72     // gemm epilogue LDS row stride: 72 elems (bf16) / 72 bytes (fp8)
#define NBUCK 391   // buckets of 256 nodes: dst>>8, 391*256 = 100096 >= 100000
#define EBCAP 5120  // per-bucket edge capacity: mean 4090, sigma 64 -> +16 sigma
#define EPB 4096    // edges per block in scatter kernel (391 blocks; r21 probe showed
                    // more blocks exports cost to atomic chains + write amp -> keep 4096)
#define NBLK_E ((NEDGES + EPB - 1) / EPB)

typedef __attribute__((ext_vector_type(8))) short bf16x8;
typedef __attribute__((ext_vector_type(4))) float f32x4;
typedef __attribute__((ext_vector_type(2))) float f32x2;
typedef unsigned char u8;
typedef unsigned short u16;
typedef unsigned int u32;
typedef unsigned long long u64;

__device__ __forceinline__ u16 f2bf(float f) {
    u32 u = __float_as_uint(f);
    u += 0x7fffu + ((u >> 16) & 1u);   // round-to-nearest-even
    return (u16)(u >> 16);
}
__device__ __forceinline__ u32 pack_bf(float a, float b) {
    return (u32)f2bf(a) | ((u32)f2bf(b) << 16);
}

// async global->LDS, 16 B per lane; LDS dest = uniform base + lane*16
__device__ __forceinline__ void gload_lds16(const u16* g, u16* l) {
    __builtin_amdgcn_global_load_lds(
        (const __attribute__((address_space(1))) u32*)g,
        (__attribute__((address_space(3))) u32*)l, 16, 0, 0);
}

// ---------------- dtype conversion ----------------

__global__ __launch_bounds__(256) void conv_x(const float* __restrict__ x,
                                              u16* __restrict__ xb,
                                              u8* __restrict__ x8) {
    int i = (blockIdx.x * 256 + threadIdx.x) * 4;
    if (i < NNODES * FDIM) {
        float4 v = *(const float4*)(x + i);
        u32 p0 = pack_bf(v.x, v.y), p1 = pack_bf(v.z, v.w);
        *(u32*)(xb + i) = p0;
        *(u32*)(xb + i + 2) = p1;
        u32 a = (u32)__builtin_amdgcn_cvt_pk_fp8_f32(v.x, v.y, 0, 0);
        u32 b = (u32)__builtin_amdgcn_cvt_pk_fp8_f32(v.z, v.w, 0, 0);
        *(u32*)(x8 + i) = (a & 0xffffu) | (b << 16);
    }
}

// Wcat[l][n][k]: k<128 -> Wrel[k][n], k>=128 -> Wroot[k-128][n]  (transposed, concat)
__global__ __launch_bounds__(256) void conv_w(const float* __restrict__ W1_rel,
                                              const float* __restrict__ W1_root,
                                              const float* __restrict__ Wc_rel,
                                              const float* __restrict__ Wc_root,
                                              u16* __restrict__ Wcat) {
    int idx = blockIdx.x * 256 + threadIdx.x;
    if (idx >= NLAYERS * 256 * FDIM) return;
    int n = idx & 127;
    int k = (idx >> 7) & 255;
    int l = idx >> 15;
    const float* Wr = (l == 0) ? W1_rel  : Wc_rel  + (size_t)(l - 1) * FDIM * FDIM;
    const float* Wt = (l == 0) ? W1_root : Wc_root + (size_t)(l - 1) * FDIM * FDIM;
    float v = (k < 128) ? Wr[(size_t)k * FDIM + n] : Wt[(size_t)(k - 128) * FDIM + n];
    Wcat[(size_t)l * 32768 + (size_t)n * 256 + k] = f2bf(v);
}

// ---------------- setup: graph ptr (binary search) + bucket cursor init, one launch -----

__global__ __launch_bounds__(512) void setup_kernel(const int* __restrict__ batch,
                                                    int* __restrict__ gptr,
                                                    int* __restrict__ bcur) {
    int t = threadIdx.x;
    if (t < NBUCK) bcur[t] = t * EBCAP;
    if (t <= NGRAPHS) {
        int lo = 0, hi = NNODES;
        while (lo < hi) {
            int mid = (lo + hi) >> 1;
            if (batch[mid] < t) lo = mid + 1; else hi = mid;
        }
        gptr[t] = lo;
    }
}

// scatter packed (dst,src) records into fixed-capacity per-bucket streams
__global__ __launch_bounds__(256) void bucket_scatter(const int* __restrict__ src,
                                                      const int* __restrict__ dst,
                                                      int* __restrict__ bcur,
                                                      u64* __restrict__ ebuf) {
    __shared__ int cnt[NBUCK];
    for (int i = threadIdx.x; i < NBUCK; i += 256) cnt[i] = 0;
    __syncthreads();
    int e0 = blockIdx.x * EPB;
    int e1 = e0 + EPB; if (e1 > NEDGES) e1 = NEDGES;
    for (int e = e0 + threadIdx.x; e < e1; e += 256)
        atomicAdd(&cnt[dst[e] >> 8], 1);
    __syncthreads();
    for (int i = threadIdx.x; i < NBUCK; i += 256) {
        int c = cnt[i];
        if (c) cnt[i] = atomicAdd(&bcur[i], c);   // cnt[i] becomes the block's base cursor
    }
    __syncthreads();
    for (int e = e0 + threadIdx.x; e < e1; e += 256) {
        int d = dst[e], s = src[e];
        int pos = atomicAdd(&cnt[d >> 8], 1);
        ebuf[pos] = ((u64)(u32)d << 32) | (u32)s;
    }
}

// one block per bucket: stage edges in LDS (one global read), count + scan -> rowstart/
// rowend, scatter src into bucket's csr slice.
__global__ __launch_bounds__(256) void bucket_csr(const u64* __restrict__ ebuf,
                                                  const int* __restrict__ bcur,
                                                  int* __restrict__ rowstart,
                                                  int* __restrict__ rowend,
                                                  int* __restrict__ csr) {
    __shared__ u64 eb[EBCAP];          // 40 KB
    __shared__ int cur[256];
    __shared__ int sd[256];
    int b = blockIdx.x, t = threadIdx.x;
    int ebase = b * EBCAP, eend = bcur[b];
    int ne = eend - ebase;
    int n0 = b << 8;
    cur[t] = 0;
    for (int e = t; e < ne; e += 256) eb[e] = ebuf[ebase + e];
    __syncthreads();
    for (int e = t; e < ne; e += 256) {
        int d = (int)(eb[e] >> 32);
        atomicAdd(&cur[d & 255], 1);
    }
    __syncthreads();
    int v = cur[t];
    sd[t] = v;
    __syncthreads();
    for (int s = 1; s < 256; s <<= 1) {
        int add = (t >= s) ? sd[t - s] : 0;
        __syncthreads();
        sd[t] += add;
        __syncthreads();
    }
    int excl = sd[t] - v;
    cur[t] = ebase + excl;
    if (n0 + t < NNODES) {
        rowstart[n0 + t] = ebase + excl;
        rowend[n0 + t]   = ebase + excl + v;
    }
    __syncthreads();
    for (int e = t; e < ne; e += 256) {
        u64 r = eb[e];
        int d = (int)(r >> 32);
        int pos = atomicAdd(&cur[d & 255], 1);
        csr[pos] = (int)(r & 0xffffffffu);
    }
}

// ---------------- aggregation: one wave per node, fp8 gather (128 B/row) ----------------
// Tail batch: loads stay 16-deep (MLP preserved); arithmetic guarded by a WAVE-UNIFORM
// branch per slot (cnt is wave-uniform) -> dead cvt/fma skipped, bit-identical result.

__global__ __launch_bounds__(256) void agg_bf(const u8* __restrict__ h8,
                                              const int* __restrict__ rowstart,
                                              const int* __restrict__ rowend,
                                              const int* __restrict__ csr,
                                              u16* __restrict__ agg) {
    int wave = threadIdx.x >> 6;
    int lane = threadIdx.x & 63;
    int node = (blockIdx.x << 2) + wave;
    if (node >= NNODES) return;
    int e0 = rowstart[node], e1 = rowend[node];
    int cnt = e1 - e0;
    float ax = 0.f, ay = 0.f;
    if (cnt <= 64) {
        int myidx = (lane < cnt) ? csr[e0 + lane] : 0;
        int nb = (cnt + 15) >> 4;
        for (int b = 0; b < nb; ++b) {
            int base = b * 16;
            u32 vv[16];
#pragma unroll
            for (int i = 0; i < 16; ++i) {
                int s = __builtin_amdgcn_readlane(myidx, base + i);
                vv[i] = *(const u16*)(h8 + (size_t)s * FDIM + lane * 2);
            }
            if (base + 16 <= cnt) {
#pragma unroll
                for (int i = 0; i < 16; ++i) {
                    f32x2 f = __builtin_amdgcn_cvt_pk_f32_fp8((int)vv[i], 0);
                    ax += f.x; ay += f.y;
                }
            } else {
#pragma unroll
                for (int i = 0; i < 16; ++i) {
                    if (base + i < cnt) {       // wave-uniform: skips dead slots entirely
                        f32x2 f = __builtin_amdgcn_cvt_pk_f32_fp8((int)vv[i], 0);
                        ax += f.x; ay += f.y;
                    }
                }
            }
        }
    } else {
        int e = e0;
        for (; e + 8 <= e1; e += 8) {
            u32 v0 = *(const u16*)(h8 + (size_t)csr[e]     * FDIM + lane * 2);
            u32 v1 = *(const u16*)(h8 + (size_t)csr[e + 1] * FDIM + lane * 2);
            u32 v2 = *(const u16*)(h8 + (size_t)csr[e + 2] * FDIM + lane * 2);
            u32 v3 = *(const u16*)(h8 + (size_t)csr[e + 3] * FDIM + lane * 2);
            u32 v4 = *(const u16*)(h8 + (size_t)csr[e + 4] * FDIM + lane * 2);
            u32 v5 = *(const u16*)(h8 + (size_t)csr[e + 5] * FDIM + lane * 2);
            u32 v6 = *(const u16*)(h8 + (size_t)csr[e + 6] * FDIM + lane * 2);
            u32 v7 = *(const u16*)(h8 + (size_t)csr[e + 7] * FDIM + lane * 2);
            f32x2 f0 = __builtin_amdgcn_cvt_pk_f32_fp8((int)v0, 0);
            f32x2 f1 = __builtin_amdgcn_cvt_pk_f32_fp8((int)v1, 0);
            f32x2 f2 = __builtin_amdgcn_cvt_pk_f32_fp8((int)v2, 0);
            f32x2 f3 = __builtin_amdgcn_cvt_pk_f32_fp8((int)v3, 0);
            f32x2 f4 = __builtin_amdgcn_cvt_pk_f32_fp8((int)v4, 0);
            f32x2 f5 = __builtin_amdgcn_cvt_pk_f32_fp8((int)v5, 0);
            f32x2 f6 = __builtin_amdgcn_cvt_pk_f32_fp8((int)v6, 0);
            f32x2 f7 = __builtin_amdgcn_cvt_pk_f32_fp8((int)v7, 0);
            ax += f0.x + f1.x + f2.x + f3.x + f4.x + f5.x + f6.x + f7.x;
            ay += f0.y + f1.y + f2.y + f3.y + f4.y + f5.y + f6.y + f7.y;
        }
        for (; e < e1; ++e) {
            u32 v0 = *(const u16*)(h8 + (size_t)csr[e] * FDIM + lane * 2);
            f32x2 f = __builtin_amdgcn_cvt_pk_f32_fp8((int)v0, 0);
            ax += f.x; ay += f.y;
        }
    }
    ((u32*)(agg + (size_t)node * FDIM))[lane] = pack_bf(ax, ay);
}

// ---------------- MFMA GEMM, M+N-SPLIT: 64 rows x 64 cols per block ---------------------
// relu([agg|h] @ Wcat^T + b) -> hout (bf16) AND hout8 (fp8); per-graph sums into z.
// Grid = 1563 row-tiles x 2 col-halves = 3126 blocks. 4 waves (2x2), wave = 32x32
// (acc[2][2]). K=256 in 4 steps of 64. LDS 16.4 KB; resident = 8 blocks/CU (32 waves =
// occupancy cap). XOR chunk-swizzle on SOURCE and READ. last!=0: skip hout stores.

__global__ __launch_bounds__(256) void gemm_mfma(const u16* __restrict__ aggb,
                                                 const u16* __restrict__ hinb,
                                                 const u16* __restrict__ Wl,   // [128 n][256 k]
                                                 const float* __restrict__ bias,
                                                 const int* __restrict__ batch,
                                                 float* __restrict__ z, int layer, int last,
                                                 u16* __restrict__ houtb,
                                                 u8* __restrict__ hout8) {
    __shared__ u16 S[8192];             // 16384 B: As(8K)|Bs(8K); C aliases: bf16 9216 B
    __shared__ int batchs[64];          // (stride 72) + fp8 4608 B @ byte 9216 (stride 72)
    u16* As = S;                        // [64][64] bf16, swizzled 16B chunks
    u16* Bs = S + 4096;                 // [64][64] bf16 (this block's 64 W-columns)
    u8* Cs8 = (u8*)S + 9216;
    const int t = threadIdx.x;
    const int lane = t & 63;
    const int w = t >> 6;
    const int wr = w >> 1, wc = w & 1;
    const int row0 = (blockIdx.x >> 1) * 64;
    const int col0 = (blockIdx.x & 1) * 64;
    const int lr = lane & 15;

    const int srow = lane >> 3;         // staging: row 0..7 within 8-row group
    const int sq = lane & 7;            // staging: chunk slot 0..7

    f32x4 acc[2][2];
#pragma unroll
    for (int m = 0; m < 2; ++m)
#pragma unroll
        for (int n = 0; n < 2; ++n) acc[m][n] = (f32x4){0.f, 0.f, 0.f, 0.f};

    if (t < 64) batchs[t] = (row0 + t < NNODES) ? batch[row0 + t] : NGRAPHS;

    for (int kb = 0; kb < 4; ++kb) {
        const u16* xsrc = (kb < 2) ? aggb : hinb;
        const int koff = (kb & 1) * 64;
        // A: 8 blk8 sub-tiles (2 per wave), rows row0..row0+63
#pragma unroll
        for (int i = 0; i < 2; ++i) {
            int blk8 = w * 2 + i;
            int r = blk8 * 8 + srow;            // 0..63 local
            int sc = sq ^ (r & 7);
            int arow = row0 + r; if (arow > NNODES - 1) arow = NNODES - 1;
            gload_lds16(xsrc + (size_t)arow * FDIM + koff + sc * 8, As + blk8 * 512);
        }
        // B: 8 blk8 sub-tiles (2 per wave), W rows col0..col0+63
#pragma unroll
        for (int i = 0; i < 2; ++i) {
            int blk8 = w * 2 + i;
            int r = blk8 * 8 + srow;            // 0..63 local
            int sc = sq ^ (r & 7);
            gload_lds16(Wl + (size_t)(col0 + r) * 256 + kb * 64 + sc * 8, Bs + blk8 * 512);
        }
        __syncthreads();                        // drains vmcnt -> LDS tiles ready
#pragma unroll
        for (int ks = 0; ks < 2; ++ks) {
            bf16x8 a[2], b[2];
            int qr = ks * 4 + (lane >> 4);      // logical chunk 0..7
#pragma unroll
            for (int m = 0; m < 2; ++m) {
                int r = wr * 32 + m * 16 + lr;  // 0..63 local row
                int ch = qr ^ (r & 7);
                a[m] = *(const bf16x8*)&As[r * 64 + ch * 8];
            }
#pragma unroll
            for (int n = 0; n < 2; ++n) {
                int r = wc * 32 + n * 16 + lr;  // 0..63 local W-row (= output col)
                int ch = qr ^ (r & 7);
                b[n] = *(const bf16x8*)&Bs[r * 64 + ch * 8];
            }
#pragma unroll
            for (int m = 0; m < 2; ++m)
#pragma unroll
                for (int n = 0; n < 2; ++n)
                    acc[m][n] = __builtin_amdgcn_mfma_f32_16x16x32_bf16(a[m], b[n], acc[m][n], 0, 0, 0);
        }
        __syncthreads();
    }
    // epilogue: bias + relu; repack bf16 + fp8 via aliased LDS (single pass)
#pragma unroll
    for (int m = 0; m < 2; ++m) {
#pragma unroll
        for (int n = 0; n < 2; ++n) {
            int cl = wc * 32 + n * 16 + lr;     // local col 0..63
            float bb = bias[col0 + cl];
#pragma unroll
            for (int reg = 0; reg < 4; ++reg) {
                int row = wr * 32 + m * 16 + (lane >> 4) * 4 + reg;  // 0..63 local
                float v = fmaxf(acc[m][n][reg] + bb, 0.f);
                S[row * GLDC + cl] = f2bf(v);
                Cs8[row * GLDC + cl] = (u8)__builtin_amdgcn_cvt_pk_fp8_f32(v, v, 0, 0);
            }
        }
    }
    __syncthreads();
    // coalesced global stores (bf16 + fp8) — dead on the last layer
    if (!last) {
        int r = t >> 2, q = t & 3;              // 64 rows x 4 threads; 16 cols (32 B) each
        if (row0 + r < NNODES) {
#pragma unroll
            for (int j = 0; j < 2; ++j) {       // 2 x 16 B = 32 B bf16
                bf16x8 v = *(const bf16x8*)&S[r * GLDC + q * 16 + j * 8];
                *(bf16x8*)(houtb + (size_t)(row0 + r) * FDIM + col0 + q * 16 + j * 8) = v;
            }
#pragma unroll
            for (int j = 0; j < 2; ++j) {       // 2 x 8 B = 16 B fp8
                u64 v8 = *(const u64*)&Cs8[r * GLDC + q * 16 + j * 8];
                *(u64*)(hout8 + (size_t)(row0 + r) * FDIM + col0 + q * 16 + j * 8) = v8;
            }
        }
    }
    // fused pool: 4 segments of 16 rows, one thread per (col, segment)
    {
        int col = t & 63, seg = t >> 6;
        int r0 = seg * 16, r1 = r0 + 16;
        float* zl = z + (size_t)layer * FDIM + col0 + col;
        int g = batchs[r0];
        float s = 0.f;
        for (int r = r0; r < r1; ++r) {
            int gn = batchs[r];
            if (gn != g) {
                atomicAdd(zl + (size_t)g * (NLAYERS * FDIM), s);
                s = 0.f; g = gn;
            }
            s += __uint_as_float((u32)S[r * GLDC + col] << 16);   // bf16 -> f32
        }
        atomicAdd(zl + (size_t)g * (NLAYERS * FDIM), s);
    }
}

// ---------------- final MLP (mean normalization folded into z load) ----------------

__global__ __launch_bounds__(128) void mlp1(const float* __restrict__ z,
                                            const int* __restrict__ gptr,
                                            const float* __restrict__ Wl1,
                                            const float* __restrict__ bl1,
                                            float* __restrict__ z2) {
    int g = blockIdx.x, j = threadIdx.x;
    __shared__ float zs[NLAYERS * FDIM];
    int cnt = gptr[g + 1] - gptr[g]; if (cnt < 1) cnt = 1;
    float invc = 1.0f / (float)cnt;
    for (int k = j; k < NLAYERS * FDIM; k += 128)
        zs[k] = z[(size_t)g * (NLAYERS * FDIM) + k] * invc;
    __syncthreads();
    float s = bl1[j];
    for (int k = 0; k < NLAYERS * FDIM; ++k) s = fmaf(zs[k], Wl1[(size_t)k * FDIM + j], s);
    z2[(size_t)g * FDIM + j] = fmaxf(s, 0.f);
}

__global__ __launch_bounds__(128) void mlp2(const float* __restrict__ z2,
                                            const float* __restrict__ Wl2,
                                            const float* __restrict__ bl2,
                                            float* __restrict__ out) {
    int g = blockIdx.x, c = threadIdx.x;
    __shared__ float zs[FDIM];
    if (threadIdx.x < FDIM) zs[threadIdx.x] = z2[(size_t)g * FDIM + threadIdx.x];
    __syncthreads();
    if (c < NCLASS) {
        float s = bl2[c];
        for (int k = 0; k < FDIM; ++k) s = fmaf(zs[k], Wl2[(size_t)k * NCLASS + c], s);
        out[(size_t)g * NCLASS + c] = s;
    }
}

// ---------------- launch ----------------

extern "C" void kernel_launch(void* const* d_in, const int* in_sizes, int n_in,
                              void* d_out, int out_size, void* d_ws, size_t ws_size,
                              hipStream_t stream) {
    const float* x       = (const float*)d_in[0];
    const int*   ei      = (const int*)d_in[1];
    const int*   batch   = (const int*)d_in[2];
    const float* W1_rel  = (const float*)d_in[3];
    const float* b1_rel  = (const float*)d_in[4];
    const float* W1_root = (const float*)d_in[5];
    const float* Wc_rel  = (const float*)d_in[6];
    const float* bc_rel  = (const float*)d_in[7];
    const float* Wc_root = (const float*)d_in[8];
    const float* Wl1     = (const float*)d_in[9];
    const float* bl1     = (const float*)d_in[10];
    const float* Wl2     = (const float*)d_in[11];
    const float* bl2     = (const float*)d_in[12];
    float* out = (float*)d_out;

    const int* srcv = ei;            // edge_index[0]
    const int* dstv = ei + NEDGES;   // edge_index[1]

    char* ws = (char*)d_ws;
    size_t off = 0;
    auto alloc = [&](size_t bytes) -> void* {
        void* p = ws + off;
        off = (off + bytes + 255) & ~(size_t)255;
        return p;
    };
    u16* xb      = (u16*)alloc((size_t)NNODES * FDIM * 2);
    u16* hA      = (u16*)alloc((size_t)NNODES * FDIM * 2);
    u16* hB      = (u16*)alloc((size_t)NNODES * FDIM * 2);
    u16* aggb    = (u16*)alloc((size_t)NNODES * FDIM * 2);
    u8*  x8      = (u8*)alloc((size_t)NNODES * FDIM);
    u8*  h8A     = (u8*)alloc((size_t)NNODES * FDIM);
    u8*  h8B     = (u8*)alloc((size_t)NNODES * FDIM);
    u16* Wcat    = (u16*)alloc((size_t)NLAYERS * 256 * FDIM * 2);
    int* csr     = (int*)alloc((size_t)NBUCK * EBCAP * 4);
    int* rowstart= (int*)alloc((size_t)NNODES * 4);
    int* rowend  = (int*)alloc((size_t)NNODES * 4);
    int* bcur    = (int*)alloc((size_t)(NBUCK + 1) * 4);
    int* gptr    = (int*)alloc(1024);
    float* z     = (float*)alloc((size_t)(NGRAPHS + 1) * NLAYERS * FDIM * 4);
    float* z2    = (float*)alloc((size_t)NGRAPHS * FDIM * 4);
    // ebuf (16.0 MB) aliases hA+hB region: build completes before layer 0 writes hA
    u64* ebuf    = (u64*)hA;
    (void)ws_size; (void)in_sizes; (void)n_in; (void)out_size;

    hipMemsetAsync(z, 0, (size_t)(NGRAPHS + 1) * NLAYERS * FDIM * 4, stream);
    conv_x<<<(NNODES * FDIM / 4 + 255) / 256, 256, 0, stream>>>(x, xb, x8);
    conv_w<<<(NLAYERS * 256 * FDIM + 255) / 256, 256, 0, stream>>>(W1_rel, W1_root, Wc_rel, Wc_root, Wcat);
    setup_kernel<<<1, 512, 0, stream>>>(batch, gptr, bcur);
    bucket_scatter<<<NBLK_E, 256, 0, stream>>>(srcv, dstv, bcur, ebuf);
    bucket_csr<<<NBUCK, 256, 0, stream>>>(ebuf, bcur, rowstart, rowend, csr);

    const u16* hin = xb;
    const u8*  hin8 = x8;
    const int gemm_nblk = ((NNODES + 63) / 64) * 2;
    for (int l = 0; l < NLAYERS; ++l) {
        u16* hout  = (l & 1) ? hB : hA;
        u8*  hout8 = (l & 1) ? h8B : h8A;
        const u16* Wl = Wcat + (size_t)l * 256 * FDIM;
        const float* bb = (l == 0) ? b1_rel : bc_rel + (size_t)(l - 1) * FDIM;
        agg_bf<<<(NNODES + 3) / 4, 256, 0, stream>>>(hin8, rowstart, rowend, csr, aggb);
        gemm_mfma<<<gemm_nblk, 256, 0, stream>>>(aggb, hin, Wl, bb, batch, z, l,
                                                 (l == NLAYERS - 1) ? 1 : 0, hout, hout8);
        hin = hout; hin8 = hout8;
    }
    mlp1<<<NGRAPHS, 128, 0, stream>>>(z, gptr, Wl1, bl1, z2);
    mlp2<<<NGRAPHS, 128, 0, stream>>>(z2, Wl2, bl2, out);
}